// Round 12
// baseline (300.830 us; speedup 1.0000x reference)
//
#include <hip/hip_runtime.h>
#include <hip/hip_bf16.h>

typedef unsigned short u16;
typedef __attribute__((ext_vector_type(8))) short short8;
typedef __attribute__((ext_vector_type(4))) float floatx4;

#define LOG2E 1.44269504088896f
#define CEXP (0.125f * LOG2E)   // folded into Q at the QK epilogue

static __device__ __forceinline__ u16 f2b(float f) {
  union { float f; unsigned u; } v; v.f = f;
  unsigned r = v.u + 0x7fffu + ((v.u >> 16) & 1u);
  return (u16)(r >> 16);
}
static __device__ __forceinline__ float b2f(u16 b) {
  union { float f; unsigned u; } v; v.u = ((unsigned)b) << 16;
  return v.f;
}
static __device__ __forceinline__ void async16(const u16* g, u16* l) {
  __builtin_amdgcn_global_load_lds(
      (const __attribute__((address_space(1))) unsigned int*)g,
      (__attribute__((address_space(3))) unsigned int*)l, 16, 0, 0);
}
static __device__ __forceinline__ float fexp2(float x) {
  return __builtin_amdgcn_exp2f(x);
}

// ---------------- weights fp32 -> bf16 (x4 vectorized) + per-channel GN stats ----------------
// convert: 786432 vec4 threads = 3072 blocks; stats: blocks [3072, 3328)
__global__ __launch_bounds__(256) void f2b_all(
    const float* __restrict__ s0, const float* __restrict__ s1, const float* __restrict__ s2,
    const float* __restrict__ s3, const float* __restrict__ s4, const float* __restrict__ s5,
    const float* __restrict__ s6, const float* __restrict__ x,
    u16* __restrict__ d_win, u16* __restrict__ d_qkv, u16* __restrict__ d_f1,
    u16* __restrict__ d_f2, u16* __restrict__ d_wout, float2* __restrict__ cstats) {
  if (blockIdx.x >= 3072) {   // per-channel stats: one block per channel
    int c = blockIdx.x - 3072;
    const float4* p4 = (const float4*)(x + (size_t)c * 4096);
    float s = 0.f, ss = 0.f;
#pragma unroll
    for (int j = 0; j < 4; j++) {
      float4 v = p4[j * 256 + threadIdx.x];
      s += v.x + v.y + v.z + v.w;
      ss += v.x * v.x + v.y * v.y + v.z * v.z + v.w * v.w;
    }
    for (int m = 1; m < 64; m <<= 1) { s += __shfl_xor(s, m); ss += __shfl_xor(ss, m); }
    __shared__ float sb[8];
    int w = threadIdx.x >> 6;
    if ((threadIdx.x & 63) == 0) { sb[w * 2] = s; sb[w * 2 + 1] = ss; }
    __syncthreads();
    if (threadIdx.x == 0)
      cstats[c] = float2{sb[0] + sb[2] + sb[4] + sb[6], sb[1] + sb[3] + sb[5] + sb[7]};
    return;
  }
  int i = blockIdx.x * 256 + threadIdx.x;   // x4 elements per thread
  const float* src;
  u16* dst;
  if (i < 32768) { src = s0; dst = d_win; }
  else if ((i -= 32768) < 65536) { src = s1; dst = d_qkv; }
  else if ((i -= 65536) < 65536) { src = s2; dst = d_qkv + 262144; }
  else if ((i -= 65536) < 65536) { src = s3; dst = d_qkv + 524288; }
  else if ((i -= 65536) < 262144) { src = s4; dst = d_f1; }
  else if ((i -= 262144) < 262144) { src = s5; dst = d_f2; }
  else { i -= 262144; src = s6; dst = d_wout; }   // i in [0, 32768)
  float4 v = *(const float4*)&src[i * 4];
  ushort4 o;
  o.x = f2b(v.x); o.y = f2b(v.y); o.z = f2b(v.z); o.w = f2b(v.w);
  *(ushort4*)&dst[i * 4] = o;
}

// ---------------- GroupNorm apply + LDS transpose to (N,C) bf16 ----------------
__global__ __launch_bounds__(256) void gn_apply(const float* __restrict__ x, const float2* __restrict__ cstats,
                                                const float* __restrict__ gg, const float* __restrict__ gb,
                                                u16* __restrict__ hn) {
  __shared__ float tile[256 * 17];
  __shared__ float gmu[32], grs[32];
  int t = threadIdx.x;
  if (t < 32) {
    float s = 0.f, ss = 0.f;
#pragma unroll
    for (int j = 0; j < 8; j++) { float2 p = cstats[t * 8 + j]; s += p.x; ss += p.y; }
    float mu = s / 32768.f;
    gmu[t] = mu;
    grs[t] = rsqrtf(ss / 32768.f - mu * mu + 1e-5f);
  }
  __syncthreads();
  int n0 = blockIdx.x * 16;
#pragma unroll
  for (int j = 0; j < 4; j++) {
    int c = j * 64 + (t >> 2);
    int nl = (t & 3) * 4;
    float4 v = *(const float4*)&x[(size_t)c * 4096 + n0 + nl];
    float ga = gg[c] * grs[c >> 3];
    float bb = gb[c] - gmu[c >> 3] * ga;
    tile[c * 17 + nl + 0] = v.x * ga + bb;
    tile[c * 17 + nl + 1] = v.y * ga + bb;
    tile[c * 17 + nl + 2] = v.z * ga + bb;
    tile[c * 17 + nl + 3] = v.w * ga + bb;
  }
  __syncthreads();
#pragma unroll
  for (int j = 0; j < 16; j++)
    hn[(size_t)(n0 + j) * 256 + t] = f2b(tile[t * 17 + j]);
}

#define FLAG_BIAS 1
#define FLAG_GELU 2
#define FLAG_C16 8
#define FLAG_CZ 64      // C16[z*M*N + m*N + n] = bf16(v), bias on z==0 only

// ---------------- GEMM 128x64 tile (proj_in) ----------------
__global__ __launch_bounds__(256) void gemm_bt(
    const u16* __restrict__ A, const u16* __restrict__ B, const float* __restrict__ bias,
    u16* __restrict__ C16, int M, int N, int K, int flags) {
  __shared__ u16 As[128 * 64];
  __shared__ u16 Bs[64 * 64];
  const int t = threadIdx.x;
  const int lane = t & 63;
  const int w = t >> 6;
  const int ln = lane & 15;
  const int quad = lane >> 4;
  const int m0 = blockIdx.x * 128;
  const int n0 = blockIdx.y * 64;
  const int wm = (w >> 1) * 64;
  const int wn = (w & 1) * 32;

  floatx4 acc[4][2];
#pragma unroll
  for (int i = 0; i < 4; i++)
#pragma unroll
    for (int j = 0; j < 2; j++) acc[i][j] = floatx4{0.f, 0.f, 0.f, 0.f};

  for (int k0 = 0; k0 < K; k0 += 64) {
    __syncthreads();
#pragma unroll
    for (int i = 0; i < 4; ++i) {
      int s = i * 256 + t;
      int row = s >> 3;
      int kb = (s & 7) ^ (row & 7);
      async16(A + (size_t)(m0 + row) * K + k0 + kb * 8, &As[(i * 256 + (t & ~63)) * 8]);
    }
#pragma unroll
    for (int i = 0; i < 2; ++i) {
      int s = i * 256 + t;
      int row = s >> 3;
      int kb = (s & 7) ^ (row & 7);
      async16(B + (size_t)(n0 + row) * K + k0 + kb * 8, &Bs[(i * 256 + (t & ~63)) * 8]);
    }
    __syncthreads();
#pragma unroll
    for (int ksi = 0; ksi < 2; ksi++) {
      short8 af[4], bfr[2];
      int kb = ksi * 4 + quad;
#pragma unroll
      for (int i = 0; i < 4; i++) {
        int m = wm + i * 16 + ln;
        af[i] = *(const short8*)&As[(m * 8 + (kb ^ (m & 7))) * 8];
      }
#pragma unroll
      for (int j = 0; j < 2; j++) {
        int n = wn + j * 16 + ln;
        bfr[j] = *(const short8*)&Bs[(n * 8 + (kb ^ (n & 7))) * 8];
      }
#pragma unroll
      for (int i = 0; i < 4; i++)
#pragma unroll
        for (int j = 0; j < 2; j++)
          acc[i][j] = __builtin_amdgcn_mfma_f32_16x16x32_bf16(af[i], bfr[j], acc[i][j], 0, 0, 0);
    }
  }

#pragma unroll
  for (int i = 0; i < 4; i++) {
#pragma unroll
    for (int j = 0; j < 2; j++) {
      int n = n0 + wn + j * 16 + ln;
      float bv = (flags & FLAG_BIAS) ? bias[n] : 0.f;
#pragma unroll
      for (int r = 0; r < 4; r++) {
        int m = m0 + wm + i * 16 + quad * 4 + r;
        float v = acc[i][j][r] + bv;
        if (flags & FLAG_C16) C16[(size_t)m * N + n] = f2b(v);
      }
    }
  }
}

// ---------------- GEMM 64x64 tile for proj_out: out = A@B^T + bias[m] + resid ----------------
__global__ __launch_bounds__(256) void gemm_out(
    const u16* __restrict__ A, const u16* __restrict__ B, const float* __restrict__ brow,
    const float* __restrict__ resid, float* __restrict__ C32, int N, int K) {
  __shared__ u16 As[64 * 64];
  __shared__ u16 Bs[64 * 64];
  const int t = threadIdx.x;
  const int lane = t & 63;
  const int w = t >> 6;
  const int ln = lane & 15;
  const int quad = lane >> 4;
  const int m0 = blockIdx.x * 64;
  const int n0 = blockIdx.y * 64;
  const int wm = (w >> 1) * 32;
  const int wn = (w & 1) * 32;

  floatx4 acc[2][2];
#pragma unroll
  for (int i = 0; i < 2; i++)
#pragma unroll
    for (int j = 0; j < 2; j++) acc[i][j] = floatx4{0.f, 0.f, 0.f, 0.f};

  for (int k0 = 0; k0 < K; k0 += 64) {
    __syncthreads();
#pragma unroll
    for (int i = 0; i < 2; ++i) {
      int s = i * 256 + t;
      int row = s >> 3;
      int kb = (s & 7) ^ (row & 7);
      async16(A + (size_t)(m0 + row) * K + k0 + kb * 8, &As[(i * 256 + (t & ~63)) * 8]);
    }
#pragma unroll
    for (int i = 0; i < 2; ++i) {
      int s = i * 256 + t;
      int row = s >> 3;
      int kb = (s & 7) ^ (row & 7);
      async16(B + (size_t)(n0 + row) * K + k0 + kb * 8, &Bs[(i * 256 + (t & ~63)) * 8]);
    }
    __syncthreads();
#pragma unroll
    for (int ksi = 0; ksi < 2; ksi++) {
      short8 af[2], bfr[2];
      int kb = ksi * 4 + quad;
#pragma unroll
      for (int i = 0; i < 2; i++) {
        int m = wm + i * 16 + ln;
        af[i] = *(const short8*)&As[(m * 8 + (kb ^ (m & 7))) * 8];
        int n = wn + i * 16 + ln;
        bfr[i] = *(const short8*)&Bs[(n * 8 + (kb ^ (n & 7))) * 8];
      }
#pragma unroll
      for (int i = 0; i < 2; i++)
#pragma unroll
        for (int j = 0; j < 2; j++)
          acc[i][j] = __builtin_amdgcn_mfma_f32_16x16x32_bf16(af[i], bfr[j], acc[i][j], 0, 0, 0);
    }
  }

#pragma unroll
  for (int i = 0; i < 2; i++) {
#pragma unroll
    for (int j = 0; j < 2; j++) {
      int n = n0 + wn + j * 16 + ln;
#pragma unroll
      for (int r = 0; r < 4; r++) {
        int m = m0 + wm + i * 16 + quad * 4 + r;
        C32[(size_t)m * N + n] = acc[i][j][r] + brow[m] + resid[(size_t)m * N + n];
      }
    }
  }
}

// ---------------- GEMM 128x128 tile (ff1, ff2 split-K bf16 partials) ----------------
__global__ __launch_bounds__(256) void gemm_big(
    const u16* __restrict__ A, const u16* __restrict__ B, const float* __restrict__ bias,
    u16* __restrict__ C16, int M, int N, int K, int flags) {
  __shared__ u16 As[128 * 64];
  __shared__ u16 Bs[128 * 64];
  const int t = threadIdx.x;
  const int lane = t & 63;
  const int w = t >> 6;
  const int ln = lane & 15;
  const int quad = lane >> 4;
  const int m0 = blockIdx.x * 128;
  const int n0 = blockIdx.y * 128;
  const int wm = (w >> 1) * 64;
  const int wn = (w & 1) * 64;
  const int kper = K / gridDim.z;
  const int kbeg = blockIdx.z * kper;

  floatx4 acc[4][4];
#pragma unroll
  for (int i = 0; i < 4; i++)
#pragma unroll
    for (int j = 0; j < 4; j++) acc[i][j] = floatx4{0.f, 0.f, 0.f, 0.f};

  for (int k0 = kbeg; k0 < kbeg + kper; k0 += 64) {
    __syncthreads();
#pragma unroll
    for (int i = 0; i < 4; ++i) {
      int s = i * 256 + t;
      int row = s >> 3;
      int kb = (s & 7) ^ (row & 7);
      async16(A + (size_t)(m0 + row) * K + k0 + kb * 8, &As[(i * 256 + (t & ~63)) * 8]);
      async16(B + (size_t)(n0 + row) * K + k0 + kb * 8, &Bs[(i * 256 + (t & ~63)) * 8]);
    }
    __syncthreads();
#pragma unroll
    for (int ksi = 0; ksi < 2; ksi++) {
      short8 af[4], bfr[4];
      int kb = ksi * 4 + quad;
#pragma unroll
      for (int i = 0; i < 4; i++) {
        int m = wm + i * 16 + ln;
        af[i] = *(const short8*)&As[(m * 8 + (kb ^ (m & 7))) * 8];
        int n = wn + i * 16 + ln;
        bfr[i] = *(const short8*)&Bs[(n * 8 + (kb ^ (n & 7))) * 8];
      }
#pragma unroll
      for (int i = 0; i < 4; i++)
#pragma unroll
        for (int j = 0; j < 4; j++)
          acc[i][j] = __builtin_amdgcn_mfma_f32_16x16x32_bf16(af[i], bfr[j], acc[i][j], 0, 0, 0);
    }
  }

  u16* Cdst = (flags & FLAG_CZ) ? C16 + (size_t)blockIdx.z * M * N : C16;
#pragma unroll
  for (int i = 0; i < 4; i++) {
#pragma unroll
    for (int j = 0; j < 4; j++) {
      int n = n0 + wn + j * 16 + ln;
      float bv = ((flags & FLAG_BIAS) && blockIdx.z == 0) ? bias[n] : 0.f;
#pragma unroll
      for (int r = 0; r < 4; r++) {
        int m = m0 + wm + i * 16 + quad * 4 + r;
        float v = acc[i][j][r] + bv;
        if (flags & FLAG_GELU) v = 0.5f * v * (1.f + erff(v * 0.70710678118f));
        Cdst[(size_t)m * N + n] = f2b(v);
      }
    }
  }
}

// ---------------- merged q|k + V^T GEMM, 64x128 tiles, one dispatch ----------------
__global__ __launch_bounds__(256) void gemm_qkvt(
    const u16* __restrict__ T, const u16* __restrict__ Wqkv,
    u16* __restrict__ Cq, u16* __restrict__ Ck, u16* __restrict__ CvT) {
  __shared__ u16 As[64 * 64];
  __shared__ u16 Bs[128 * 64];
  const int t = threadIdx.x;
  const int lane = t & 63;
  const int w = t >> 6;
  const int ln = lane & 15;
  const int quad = lane >> 4;
  const int bx = blockIdx.x;
  const bool isv = bx >= 512;
  const u16* A;
  const u16* B;
  int m0, n0;
  if (!isv) {
    m0 = (bx >> 3) * 64;
    n0 = (bx & 7) * 128;
    A = T;
    B = Wqkv;
  } else {
    int b2 = bx - 512;
    m0 = (b2 >> 5) * 64;
    n0 = (b2 & 31) * 128;
    A = Wqkv + 2 * 512 * 512;   // wv
    B = T;
  }
  const int wm = (w >> 1) * 32;
  const int wn = (w & 1) * 64;

  floatx4 acc[2][4];
#pragma unroll
  for (int i = 0; i < 2; i++)
#pragma unroll
    for (int j = 0; j < 4; j++) acc[i][j] = floatx4{0.f, 0.f, 0.f, 0.f};

  for (int k0 = 0; k0 < 512; k0 += 64) {
    __syncthreads();
#pragma unroll
    for (int i = 0; i < 2; ++i) {
      int s = i * 256 + t;
      int row = s >> 3;
      int kb = (s & 7) ^ (row & 7);
      async16(A + (size_t)(m0 + row) * 512 + k0 + kb * 8, &As[(i * 256 + (t & ~63)) * 8]);
    }
#pragma unroll
    for (int i = 0; i < 4; ++i) {
      int s = i * 256 + t;
      int row = s >> 3;
      int kb = (s & 7) ^ (row & 7);
      async16(B + (size_t)(n0 + row) * 512 + k0 + kb * 8, &Bs[(i * 256 + (t & ~63)) * 8]);
    }
    __syncthreads();
#pragma unroll
    for (int ksi = 0; ksi < 2; ksi++) {
      short8 af[2], bfr[4];
      int kb = ksi * 4 + quad;
#pragma unroll
      for (int i = 0; i < 2; i++) {
        int m = wm + i * 16 + ln;
        af[i] = *(const short8*)&As[(m * 8 + (kb ^ (m & 7))) * 8];
      }
#pragma unroll
      for (int j = 0; j < 4; j++) {
        int n = wn + j * 16 + ln;
        bfr[j] = *(const short8*)&Bs[(n * 8 + (kb ^ (n & 7))) * 8];
      }
#pragma unroll
      for (int i = 0; i < 2; i++)
#pragma unroll
        for (int j = 0; j < 4; j++)
          acc[i][j] = __builtin_amdgcn_mfma_f32_16x16x32_bf16(af[i], bfr[j], acc[i][j], 0, 0, 0);
    }
  }

#pragma unroll
  for (int i = 0; i < 2; i++) {
#pragma unroll
    for (int j = 0; j < 4; j++) {
      int n = n0 + wn + j * 16 + ln;
#pragma unroll
      for (int r = 0; r < 4; r++) {
        int m = m0 + wm + i * 16 + quad * 4 + r;
        float v = acc[i][j][r];
        if (isv) CvT[(size_t)m * 4096 + n] = f2b(v);
        else if (n < 512) Cq[(size_t)m * 512 + n] = f2b(v * CEXP);   // Q pre-scaled
        else Ck[(size_t)m * 512 + (n - 512)] = f2b(v);
      }
    }
  }
}

// ---------------- flash attention: BARRIER-FREE ----------------
// K/V fragments loaded directly from global (16B/lane contiguous, 4 lanes share a
// 64B line, L2-served since each tile is reused by 32 q-blocks). Only P round-trips
// through wave-private LDS (in-wave lgkmcnt ordering, no __syncthreads anywhere).
__global__ __launch_bounds__(256, 4) void attn_kernel(
    const u16* __restrict__ Q, const u16* __restrict__ Km, const u16* __restrict__ VT,
    u16* __restrict__ Opart, float* __restrict__ ML, int Nseq, int kvLen) {
  __shared__ u16 Ps[4 * 32 * 64];
  const int t = threadIdx.x;
  const int lane = t & 63;
  const int w = t >> 6;
  const int ln = lane & 15;
  const int quad = lane >> 4;
  const int h = blockIdx.y;
  const int q0 = blockIdx.x * 128;
  const int split = blockIdx.z;
  const int kvbase = split * kvLen;
  u16* Opw = Opart + (size_t)split * Nseq * 512;
  u16* Pw = &Ps[w * 32 * 64];

  short8 qf[2][2];
#pragma unroll
  for (int qt = 0; qt < 2; qt++)
#pragma unroll
    for (int ksi = 0; ksi < 2; ksi++)
      qf[qt][ksi] = *(const short8*)&Q[(size_t)(q0 + w * 32 + qt * 16 + ln) * 512 + h * 64 + ksi * 32 + quad * 8];

  floatx4 accO[2][4];
#pragma unroll
  for (int qt = 0; qt < 2; qt++)
#pragma unroll
    for (int td = 0; td < 4; td++) accO[qt][td] = floatx4{0.f, 0.f, 0.f, 0.f};
  float lsum[2] = {0.f, 0.f};

  // per-lane fragment base pointers (bumped per kv-tile)
  const u16* Kp = Km + (size_t)(kvbase + ln) * 512 + h * 64 + quad * 8;
  const u16* Vp = VT + (size_t)(h * 64 + ln) * Nseq + kvbase + quad * 8;

  for (int kv = 0; kv < kvLen; kv += 64) {
    // S^T = K.Q^T, K-frags straight from global
    floatx4 accS[2][4];
#pragma unroll
    for (int qt = 0; qt < 2; qt++)
#pragma unroll
      for (int tj = 0; tj < 4; tj++) accS[qt][tj] = floatx4{0.f, 0.f, 0.f, 0.f};
#pragma unroll
    for (int ksi = 0; ksi < 2; ksi++) {
      short8 kf[4];
#pragma unroll
      for (int tj = 0; tj < 4; tj++)
        kf[tj] = *(const short8*)&Kp[(size_t)(tj * 16) * 512 + ksi * 32];
#pragma unroll
      for (int qt = 0; qt < 2; qt++)
#pragma unroll
        for (int tj = 0; tj < 4; tj++)
          accS[qt][tj] = __builtin_amdgcn_mfma_f32_16x16x32_bf16(kf[tj], qf[qt][ksi], accS[qt][tj], 0, 0, 0);
    }

    // p = exp2(s); per-lane l; pack to wave-private LDS (swizzled)
#pragma unroll
    for (int qt = 0; qt < 2; qt++) {
      int q8 = (qt * 16 + ln) * 8;
#pragma unroll
      for (int tj = 0; tj < 4; tj++) {
        float p0 = fexp2(accS[qt][tj][0]);
        float p1 = fexp2(accS[qt][tj][1]);
        float p2 = fexp2(accS[qt][tj][2]);
        float p3 = fexp2(accS[qt][tj][3]);
        lsum[qt] += (p0 + p1) + (p2 + p3);
        __hip_bfloat162 a01 = __float22bfloat162_rn(float2{p0, p1});
        __hip_bfloat162 a23 = __float22bfloat162_rn(float2{p2, p3});
        uint2 pk;
        pk.x = *(unsigned*)&a01;
        pk.y = *(unsigned*)&a23;
        int kbx = tj * 2 + (quad >> 1);
        *(uint2*)&Pw[(q8 + (kbx ^ (ln & 7))) * 8 + (quad & 1) * 4] = pk;
      }
    }

    // O^T += V^T . P^T, V-frags straight from global
#pragma unroll
    for (int ksi = 0; ksi < 2; ksi++) {
      int kb = ksi * 4 + quad;
      short8 pf[2];
#pragma unroll
      for (int qt = 0; qt < 2; qt++)
        pf[qt] = *(const short8*)&Pw[((qt * 16 + ln) * 8 + (kb ^ (ln & 7))) * 8];
#pragma unroll
      for (int td = 0; td < 4; td++) {
        short8 vf = *(const short8*)&Vp[(size_t)(td * 16) * Nseq + ksi * 32];
#pragma unroll
        for (int qt = 0; qt < 2; qt++)
          accO[qt][td] = __builtin_amdgcn_mfma_f32_16x16x32_bf16(vf, pf[qt], accO[qt][td], 0, 0, 0);
      }
    }
    Kp += 64 * 512;
    Vp += 64;
  }

#pragma unroll
  for (int qt = 0; qt < 2; qt++) {
    lsum[qt] += __shfl_xor(lsum[qt], 16);
    lsum[qt] += __shfl_xor(lsum[qt], 32);
  }
#pragma unroll
  for (int qt = 0; qt < 2; qt++) {
    int q = q0 + w * 32 + qt * 16 + ln;
#pragma unroll
    for (int td = 0; td < 4; td++) {
      __hip_bfloat162 p01 = __float22bfloat162_rn(float2{accO[qt][td][0], accO[qt][td][1]});
      __hip_bfloat162 p23 = __float22bfloat162_rn(float2{accO[qt][td][2], accO[qt][td][3]});
      uint2 pk;
      pk.x = *(unsigned*)&p01;
      pk.y = *(unsigned*)&p23;
      *(uint2*)&Opw[(size_t)q * 512 + h * 64 + td * 16 + quad * 4] = pk;
    }
    if (quad == 0)
      ML[((size_t)split * 8 + h) * Nseq + q] = lsum[qt];
  }
}

// ---------------- combine 4 splits + bf16 residual + LayerNorm (ln1) -> bf16 ----------------
__global__ __launch_bounds__(256) void ln_attn(
    const u16* __restrict__ Opart, const float* __restrict__ ML,
    const u16* __restrict__ t16, const float* __restrict__ g, const float* __restrict__ be,
    u16* __restrict__ o16) {
  int row = blockIdx.x;
  int t = threadIdx.x;
  size_t base = (size_t)row * 512;
  int c0 = 2 * t;
  int h = c0 >> 6;
  float lt = 0.f;
#pragma unroll
  for (int s = 0; s < 4; s++) lt += ML[((size_t)s * 8 + h) * 4096 + row];
  float a0 = 0.f, a1 = 0.f;
#pragma unroll
  for (int s = 0; s < 4; s++) {
    unsigned oo = *(const unsigned*)&Opart[(size_t)s * 4096 * 512 + base + c0];
    a0 += b2f((u16)(oo & 0xffff));
    a1 += b2f((u16)(oo >> 16));
  }
  unsigned tt = *(const unsigned*)&t16[base + c0];
  float inv = 1.0f / lt;
  float v0 = a0 * inv + b2f((u16)(tt & 0xffff));
  float v1 = a1 * inv + b2f((u16)(tt >> 16));
  float s = v0 + v1, ss = v0 * v0 + v1 * v1;
  for (int m = 1; m < 64; m <<= 1) { s += __shfl_xor(s, m); ss += __shfl_xor(ss, m); }
  __shared__ float sb[8];
  int w = t >> 6;
  if ((t & 63) == 0) { sb[w * 2] = s; sb[w * 2 + 1] = ss; }
  __syncthreads();
  s = sb[0] + sb[2] + sb[4] + sb[6];
  ss = sb[1] + sb[3] + sb[5] + sb[7];
  float mu = s / 512.f;
  float var = ss / 512.f - mu * mu;
  float rs = rsqrtf(var + 1e-5f);
  float2 gv = *(const float2*)&g[c0];
  float2 bv = *(const float2*)&be[c0];
  u16 r0 = f2b((v0 - mu) * rs * gv.x + bv.x);
  u16 r1 = f2b((v1 - mu) * rs * gv.y + bv.y);
  *(unsigned*)&o16[base + c0] = ((unsigned)r1 << 16) | r0;
}

// ---------------- LN2: (4 bf16 split-K partials + bf16 u) -> LayerNorm -> bf16 ----------------
__global__ __launch_bounds__(256) void ln_ff(
    const u16* __restrict__ zp, const u16* __restrict__ u,
    const float* __restrict__ g, const float* __restrict__ be, u16* __restrict__ o16) {
  int row = blockIdx.x;
  int t = threadIdx.x;
  size_t base = (size_t)row * 512;
  int c0 = 2 * t;
  unsigned uu = *(const unsigned*)&u[base + c0];
  float v0 = b2f((u16)(uu & 0xffff));
  float v1 = b2f((u16)(uu >> 16));
#pragma unroll
  for (int z = 0; z < 4; z++) {
    unsigned zz = *(const unsigned*)&zp[(size_t)z * 4096 * 512 + base + c0];
    v0 += b2f((u16)(zz & 0xffff));
    v1 += b2f((u16)(zz >> 16));
  }
  float s = v0 + v1, ss = v0 * v0 + v1 * v1;
  for (int m = 1; m < 64; m <<= 1) { s += __shfl_xor(s, m); ss += __shfl_xor(ss, m); }
  __shared__ float sb[8];
  int w = t >> 6;
  if ((t & 63) == 0) { sb[w * 2] = s; sb[w * 2 + 1] = ss; }
  __syncthreads();
  s = sb[0] + sb[2] + sb[4] + sb[6];
  ss = sb[1] + sb[3] + sb[5] + sb[7];
  float mu = s / 512.f;
  float var = ss / 512.f - mu * mu;
  float rs = rsqrtf(var + 1e-5f);
  float2 gv = *(const float2*)&g[c0];
  float2 bv = *(const float2*)&be[c0];
  u16 r0 = f2b((v0 - mu) * rs * gv.x + bv.x);
  u16 r1 = f2b((v1 - mu) * rs * gv.y + bv.y);
  *(unsigned*)&o16[base + c0] = ((unsigned)r1 << 16) | r0;
}

extern "C" void kernel_launch(void* const* d_in, const int* in_sizes, int n_in,
                              void* d_out, int out_size, void* d_ws, size_t ws_size,
                              hipStream_t stream) {
  const float* x = (const float*)d_in[0];
  const float* gn_g = (const float*)d_in[1];
  const float* gn_b = (const float*)d_in[2];
  const float* w_in = (const float*)d_in[3];
  const float* b_in = (const float*)d_in[4];
  const float* wq = (const float*)d_in[5];
  const float* wk = (const float*)d_in[6];
  const float* wv = (const float*)d_in[7];
  const float* ln1_g = (const float*)d_in[8];
  const float* ln1_b = (const float*)d_in[9];
  const float* ff_w1 = (const float*)d_in[10];
  const float* ff_b1 = (const float*)d_in[11];
  const float* ff_w2 = (const float*)d_in[12];
  const float* ff_b2 = (const float*)d_in[13];
  const float* ln2_g = (const float*)d_in[14];
  const float* ln2_b = (const float*)d_in[15];
  const float* w_out = (const float*)d_in[16];
  const float* b_out = (const float*)d_in[17];
  float* out = (float*)d_out;
  char* ws = (char*)d_ws;

  // ---- workspace layout (byte offsets; lifetime-audited) ----
  u16* w_in16 = (u16*)(ws + 0);                  // 0-0.25 MiB
  u16* wqkv16 = (u16*)(ws + 262144);             // 0.25-1.75 (wq|wk|wv)
  u16* fw116 = (u16*)(ws + 1835008);             // 1.75-3.75
  u16* fw216 = (u16*)(ws + 3932160);             // 3.75-5.75
  u16* wout16 = (u16*)(ws + 6029312);            // 5.75-6
  u16* u16b = (u16*)(ws + 6291456);              // 6-10   ln_attn -> ff1, ln_ff
  u16* zp = (u16*)(ws + 10485760);               // 10-26  ff2 partials -> ln_ff (over t16/qb/kb, dead)
  u16* t16 = (u16*)(ws + 14680064);              // 14-18  proj_in -> qkvt, ln_attn
  u16* qb = (u16*)(ws + 18874368);               // 18-22  qkvt -> attn
  u16* kb = (u16*)(ws + 23068672);               // 22-26  qkvt -> attn
  u16* vt = (u16*)(ws + 27262976);               // 26-30  qkvt -> attn
  u16* zb = (u16*)(ws + 27262976);               // 26-30  ln_ff -> proj_out (over vt, dead)
  u16* opart = (u16*)(ws + 31457280);            // 30-46  attn -> ln_attn (4 splits)
  u16* g16 = (u16*)(ws + 31457280);              // 30-46  ff1 -> ff2 (over opart, dead)
  float* ml = (float*)(ws + 48234496);           // 46-46.5 attn -> ln_attn
  u16* hn = (u16*)(ws + 49283072);               // 47-49  gn -> proj_in
  float2* cstats = (float2*)(ws + 51380224);     // 49+

  // weights convert (x4 vectorized, 3072 blocks) + per-channel GN stats (256 blocks)
  f2b_all<<<3328, 256, 0, stream>>>(w_in, wq, wk, wv, ff_w1, ff_w2, w_out, x,
                                    w_in16, wqkv16, fw116, fw216, wout16, cstats);
  gn_apply<<<256, 256, 0, stream>>>(x, cstats, gn_g, gn_b, hn);

  // t = hn @ w_in^T + b_in  -> bf16 only
  gemm_bt<<<dim3(32, 8), 256, 0, stream>>>(hn, w_in16, b_in, t16,
                                           4096, 512, 256, FLAG_BIAS | FLAG_C16);
  // fused q|k (+CEXP on q) and V^T, one dispatch, 768 blocks
  gemm_qkvt<<<768, 256, 0, stream>>>(t16, wqkv16, qb, kb, vt);
  // attention: 128q/block, KV-split x4, barrier-free direct-global K/V
  attn_kernel<<<dim3(32, 8, 4), 256, 0, stream>>>(qb, kb, vt, opart, ml, 4096, 1024);
  // combine + LN1 (residual from t16) -> bf16
  ln_attn<<<4096, 256, 0, stream>>>(opart, ml, t16, ln1_g, ln1_b, u16b);
  // ff1: gelu(u @ w1^T + b1) -> bf16
  gemm_big<<<dim3(32, 16), 256, 0, stream>>>(u16b, fw116, ff_b1, g16,
                                             4096, 2048, 512, FLAG_BIAS | FLAG_GELU | FLAG_C16);
  // ff2: split-K x4 -> four bf16 partials
  gemm_big<<<dim3(32, 4, 4), 256, 0, stream>>>(g16, fw216, ff_b2, zp,
                                               4096, 512, 2048, FLAG_BIAS | FLAG_CZ);
  // z = LN(sum zp + u) -> bf16
  ln_ff<<<4096, 256, 0, stream>>>(zp, u16b, ln2_g, ln2_b, zb);
  // out = W_out @ z^T (+b_out per-row, +x), 64x64 tiles, 256 blocks
  gemm_out<<<dim3(4, 64), 256, 0, stream>>>(wout16, zb, b_out, x, out, 4096, 512);
}

// Round 13
// 227.826 us; speedup vs baseline: 1.3204x; 1.3204x over previous
//
#include <hip/hip_runtime.h>
#include <hip/hip_bf16.h>

typedef unsigned short u16;
typedef __attribute__((ext_vector_type(8))) short short8;
typedef __attribute__((ext_vector_type(4))) float floatx4;

#define LOG2E 1.44269504088896f
#define CEXP (0.125f * LOG2E)   // folded into Q at the QK epilogue

static __device__ __forceinline__ u16 f2b(float f) {
  union { float f; unsigned u; } v; v.f = f;
  unsigned r = v.u + 0x7fffu + ((v.u >> 16) & 1u);
  return (u16)(r >> 16);
}
static __device__ __forceinline__ float b2f(u16 b) {
  union { float f; unsigned u; } v; v.u = ((unsigned)b) << 16;
  return v.f;
}
static __device__ __forceinline__ void async16(const u16* g, u16* l) {
  __builtin_amdgcn_global_load_lds(
      (const __attribute__((address_space(1))) unsigned int*)g,
      (__attribute__((address_space(3))) unsigned int*)l, 16, 0, 0);
}
static __device__ __forceinline__ float fexp2(float x) {
  return __builtin_amdgcn_exp2f(x);
}

// ---------------- weights fp32 -> bf16 (x4 vectorized) + per-channel GN stats ----------------
__global__ __launch_bounds__(256) void f2b_all(
    const float* __restrict__ s0, const float* __restrict__ s1, const float* __restrict__ s2,
    const float* __restrict__ s3, const float* __restrict__ s4, const float* __restrict__ s5,
    const float* __restrict__ s6, const float* __restrict__ x,
    u16* __restrict__ d_win, u16* __restrict__ d_qkv, u16* __restrict__ d_f1,
    u16* __restrict__ d_f2, u16* __restrict__ d_wout, float2* __restrict__ cstats) {
  if (blockIdx.x >= 3072) {   // per-channel stats: one block per channel
    int c = blockIdx.x - 3072;
    const float4* p4 = (const float4*)(x + (size_t)c * 4096);
    float s = 0.f, ss = 0.f;
#pragma unroll
    for (int j = 0; j < 4; j++) {
      float4 v = p4[j * 256 + threadIdx.x];
      s += v.x + v.y + v.z + v.w;
      ss += v.x * v.x + v.y * v.y + v.z * v.z + v.w * v.w;
    }
    for (int m = 1; m < 64; m <<= 1) { s += __shfl_xor(s, m); ss += __shfl_xor(ss, m); }
    __shared__ float sb[8];
    int w = threadIdx.x >> 6;
    if ((threadIdx.x & 63) == 0) { sb[w * 2] = s; sb[w * 2 + 1] = ss; }
    __syncthreads();
    if (threadIdx.x == 0)
      cstats[c] = float2{sb[0] + sb[2] + sb[4] + sb[6], sb[1] + sb[3] + sb[5] + sb[7]};
    return;
  }
  int i = blockIdx.x * 256 + threadIdx.x;   // x4 elements per thread
  const float* src;
  u16* dst;
  if (i < 32768) { src = s0; dst = d_win; }
  else if ((i -= 32768) < 65536) { src = s1; dst = d_qkv; }
  else if ((i -= 65536) < 65536) { src = s2; dst = d_qkv + 262144; }
  else if ((i -= 65536) < 65536) { src = s3; dst = d_qkv + 524288; }
  else if ((i -= 65536) < 262144) { src = s4; dst = d_f1; }
  else if ((i -= 262144) < 262144) { src = s5; dst = d_f2; }
  else { i -= 262144; src = s6; dst = d_wout; }   // i in [0, 32768)
  float4 v = *(const float4*)&src[i * 4];
  ushort4 o;
  o.x = f2b(v.x); o.y = f2b(v.y); o.z = f2b(v.z); o.w = f2b(v.w);
  *(ushort4*)&dst[i * 4] = o;
}

// ---------------- GroupNorm apply + LDS transpose to (N,C) bf16 ----------------
__global__ __launch_bounds__(256) void gn_apply(const float* __restrict__ x, const float2* __restrict__ cstats,
                                                const float* __restrict__ gg, const float* __restrict__ gb,
                                                u16* __restrict__ hn) {
  __shared__ float tile[256 * 17];
  __shared__ float gmu[32], grs[32];
  int t = threadIdx.x;
  if (t < 32) {
    float s = 0.f, ss = 0.f;
#pragma unroll
    for (int j = 0; j < 8; j++) { float2 p = cstats[t * 8 + j]; s += p.x; ss += p.y; }
    float mu = s / 32768.f;
    gmu[t] = mu;
    grs[t] = rsqrtf(ss / 32768.f - mu * mu + 1e-5f);
  }
  __syncthreads();
  int n0 = blockIdx.x * 16;
#pragma unroll
  for (int j = 0; j < 4; j++) {
    int c = j * 64 + (t >> 2);
    int nl = (t & 3) * 4;
    float4 v = *(const float4*)&x[(size_t)c * 4096 + n0 + nl];
    float ga = gg[c] * grs[c >> 3];
    float bb = gb[c] - gmu[c >> 3] * ga;
    tile[c * 17 + nl + 0] = v.x * ga + bb;
    tile[c * 17 + nl + 1] = v.y * ga + bb;
    tile[c * 17 + nl + 2] = v.z * ga + bb;
    tile[c * 17 + nl + 3] = v.w * ga + bb;
  }
  __syncthreads();
#pragma unroll
  for (int j = 0; j < 16; j++)
    hn[(size_t)(n0 + j) * 256 + t] = f2b(tile[t * 17 + j]);
}

#define FLAG_BIAS 1
#define FLAG_GELU 2
#define FLAG_C16 8
#define FLAG_FINAL 32   // C32[m*N+n] = v + bias[m] + resid[m*N+n]
#define FLAG_CZ 64      // C16[z*M*N + m*N + n] = bf16(v), bias on z==0 only

// ---------------- GEMM 64x64 tile (proj_in: bias+bf16 out; proj_out: row-bias+resid fp32) ----------------
__global__ __launch_bounds__(256) void gemm_s64(
    const u16* __restrict__ A, const u16* __restrict__ B, const float* __restrict__ bias,
    const float* __restrict__ resid, float* __restrict__ C32, u16* __restrict__ C16,
    int M, int N, int K, int flags) {
  __shared__ u16 As[64 * 64];
  __shared__ u16 Bs[64 * 64];
  const int t = threadIdx.x;
  const int lane = t & 63;
  const int w = t >> 6;
  const int ln = lane & 15;
  const int quad = lane >> 4;
  const int m0 = blockIdx.x * 64;
  const int n0 = blockIdx.y * 64;
  const int wm = (w >> 1) * 32;
  const int wn = (w & 1) * 32;

  floatx4 acc[2][2];
#pragma unroll
  for (int i = 0; i < 2; i++)
#pragma unroll
    for (int j = 0; j < 2; j++) acc[i][j] = floatx4{0.f, 0.f, 0.f, 0.f};

  for (int k0 = 0; k0 < K; k0 += 64) {
    __syncthreads();
#pragma unroll
    for (int i = 0; i < 2; ++i) {
      int s = i * 256 + t;
      int row = s >> 3;
      int kb = (s & 7) ^ (row & 7);
      async16(A + (size_t)(m0 + row) * K + k0 + kb * 8, &As[(i * 256 + (t & ~63)) * 8]);
    }
#pragma unroll
    for (int i = 0; i < 2; ++i) {
      int s = i * 256 + t;
      int row = s >> 3;
      int kb = (s & 7) ^ (row & 7);
      async16(B + (size_t)(n0 + row) * K + k0 + kb * 8, &Bs[(i * 256 + (t & ~63)) * 8]);
    }
    __syncthreads();
#pragma unroll
    for (int ksi = 0; ksi < 2; ksi++) {
      short8 af[2], bfr[2];
      int kb = ksi * 4 + quad;
#pragma unroll
      for (int i = 0; i < 2; i++) {
        int m = wm + i * 16 + ln;
        af[i] = *(const short8*)&As[(m * 8 + (kb ^ (m & 7))) * 8];
        int n = wn + i * 16 + ln;
        bfr[i] = *(const short8*)&Bs[(n * 8 + (kb ^ (n & 7))) * 8];
      }
#pragma unroll
      for (int i = 0; i < 2; i++)
#pragma unroll
        for (int j = 0; j < 2; j++)
          acc[i][j] = __builtin_amdgcn_mfma_f32_16x16x32_bf16(af[i], bfr[j], acc[i][j], 0, 0, 0);
    }
  }

#pragma unroll
  for (int i = 0; i < 2; i++) {
#pragma unroll
    for (int j = 0; j < 2; j++) {
      int n = n0 + wn + j * 16 + ln;
      float bv = (flags & FLAG_BIAS) ? bias[n] : 0.f;
#pragma unroll
      for (int r = 0; r < 4; r++) {
        int m = m0 + wm + i * 16 + quad * 4 + r;
        float v = acc[i][j][r] + bv;
        if (flags & FLAG_C16) C16[(size_t)m * N + n] = f2b(v);
        if (flags & FLAG_FINAL)
          C32[(size_t)m * N + n] = v + bias[m] + resid[(size_t)m * N + n];
      }
    }
  }
}

// ---------------- GEMM 128x128 tile (ff1, ff2 split-K bf16 partials) ----------------
__global__ __launch_bounds__(256) void gemm_big(
    const u16* __restrict__ A, const u16* __restrict__ B, const float* __restrict__ bias,
    u16* __restrict__ C16, int M, int N, int K, int flags) {
  __shared__ u16 As[128 * 64];
  __shared__ u16 Bs[128 * 64];
  const int t = threadIdx.x;
  const int lane = t & 63;
  const int w = t >> 6;
  const int ln = lane & 15;
  const int quad = lane >> 4;
  const int m0 = blockIdx.x * 128;
  const int n0 = blockIdx.y * 128;
  const int wm = (w >> 1) * 64;
  const int wn = (w & 1) * 64;
  const int kper = K / gridDim.z;
  const int kbeg = blockIdx.z * kper;

  floatx4 acc[4][4];
#pragma unroll
  for (int i = 0; i < 4; i++)
#pragma unroll
    for (int j = 0; j < 4; j++) acc[i][j] = floatx4{0.f, 0.f, 0.f, 0.f};

  for (int k0 = kbeg; k0 < kbeg + kper; k0 += 64) {
    __syncthreads();
#pragma unroll
    for (int i = 0; i < 4; ++i) {
      int s = i * 256 + t;
      int row = s >> 3;
      int kb = (s & 7) ^ (row & 7);
      async16(A + (size_t)(m0 + row) * K + k0 + kb * 8, &As[(i * 256 + (t & ~63)) * 8]);
      async16(B + (size_t)(n0 + row) * K + k0 + kb * 8, &Bs[(i * 256 + (t & ~63)) * 8]);
    }
    __syncthreads();
#pragma unroll
    for (int ksi = 0; ksi < 2; ksi++) {
      short8 af[4], bfr[4];
      int kb = ksi * 4 + quad;
#pragma unroll
      for (int i = 0; i < 4; i++) {
        int m = wm + i * 16 + ln;
        af[i] = *(const short8*)&As[(m * 8 + (kb ^ (m & 7))) * 8];
        int n = wn + i * 16 + ln;
        bfr[i] = *(const short8*)&Bs[(n * 8 + (kb ^ (n & 7))) * 8];
      }
#pragma unroll
      for (int i = 0; i < 4; i++)
#pragma unroll
        for (int j = 0; j < 4; j++)
          acc[i][j] = __builtin_amdgcn_mfma_f32_16x16x32_bf16(af[i], bfr[j], acc[i][j], 0, 0, 0);
    }
  }

  u16* Cdst = (flags & FLAG_CZ) ? C16 + (size_t)blockIdx.z * M * N : C16;
#pragma unroll
  for (int i = 0; i < 4; i++) {
#pragma unroll
    for (int j = 0; j < 4; j++) {
      int n = n0 + wn + j * 16 + ln;
      float bv = ((flags & FLAG_BIAS) && blockIdx.z == 0) ? bias[n] : 0.f;
#pragma unroll
      for (int r = 0; r < 4; r++) {
        int m = m0 + wm + i * 16 + quad * 4 + r;
        float v = acc[i][j][r] + bv;
        if (flags & FLAG_GELU) v = 0.5f * v * (1.f + erff(v * 0.70710678118f));
        Cdst[(size_t)m * N + n] = f2b(v);
      }
    }
  }
}

// ---------------- merged q|k + V^T GEMM, 64x128 tiles, one dispatch ----------------
__global__ __launch_bounds__(256) void gemm_qkvt(
    const u16* __restrict__ T, const u16* __restrict__ Wqkv,
    u16* __restrict__ Cq, u16* __restrict__ Ck, u16* __restrict__ CvT) {
  __shared__ u16 As[64 * 64];
  __shared__ u16 Bs[128 * 64];
  const int t = threadIdx.x;
  const int lane = t & 63;
  const int w = t >> 6;
  const int ln = lane & 15;
  const int quad = lane >> 4;
  const int bx = blockIdx.x;
  const bool isv = bx >= 512;
  const u16* A;
  const u16* B;
  int m0, n0;
  if (!isv) {
    m0 = (bx >> 3) * 64;
    n0 = (bx & 7) * 128;
    A = T;
    B = Wqkv;
  } else {
    int b2 = bx - 512;
    m0 = (b2 >> 5) * 64;
    n0 = (b2 & 31) * 128;
    A = Wqkv + 2 * 512 * 512;   // wv
    B = T;
  }
  const int wm = (w >> 1) * 32;
  const int wn = (w & 1) * 64;

  floatx4 acc[2][4];
#pragma unroll
  for (int i = 0; i < 2; i++)
#pragma unroll
    for (int j = 0; j < 4; j++) acc[i][j] = floatx4{0.f, 0.f, 0.f, 0.f};

  for (int k0 = 0; k0 < 512; k0 += 64) {
    __syncthreads();
#pragma unroll
    for (int i = 0; i < 2; ++i) {
      int s = i * 256 + t;
      int row = s >> 3;
      int kb = (s & 7) ^ (row & 7);
      async16(A + (size_t)(m0 + row) * 512 + k0 + kb * 8, &As[(i * 256 + (t & ~63)) * 8]);
    }
#pragma unroll
    for (int i = 0; i < 4; ++i) {
      int s = i * 256 + t;
      int row = s >> 3;
      int kb = (s & 7) ^ (row & 7);
      async16(B + (size_t)(n0 + row) * 512 + k0 + kb * 8, &Bs[(i * 256 + (t & ~63)) * 8]);
    }
    __syncthreads();
#pragma unroll
    for (int ksi = 0; ksi < 2; ksi++) {
      short8 af[2], bfr[4];
      int kb = ksi * 4 + quad;
#pragma unroll
      for (int i = 0; i < 2; i++) {
        int m = wm + i * 16 + ln;
        af[i] = *(const short8*)&As[(m * 8 + (kb ^ (m & 7))) * 8];
      }
#pragma unroll
      for (int j = 0; j < 4; j++) {
        int n = wn + j * 16 + ln;
        bfr[j] = *(const short8*)&Bs[(n * 8 + (kb ^ (n & 7))) * 8];
      }
#pragma unroll
      for (int i = 0; i < 2; i++)
#pragma unroll
        for (int j = 0; j < 4; j++)
          acc[i][j] = __builtin_amdgcn_mfma_f32_16x16x32_bf16(af[i], bfr[j], acc[i][j], 0, 0, 0);
    }
  }

#pragma unroll
  for (int i = 0; i < 2; i++) {
#pragma unroll
    for (int j = 0; j < 4; j++) {
      int n = n0 + wn + j * 16 + ln;
#pragma unroll
      for (int r = 0; r < 4; r++) {
        int m = m0 + wm + i * 16 + quad * 4 + r;
        float v = acc[i][j][r];
        if (isv) CvT[(size_t)m * 4096 + n] = f2b(v);
        else if (n < 512) Cq[(size_t)m * 512 + n] = f2b(v * CEXP);   // Q pre-scaled
        else Ck[(size_t)m * 512 + (n - 512)] = f2b(v);
      }
    }
  }
}

// ---------------- flash attention: S^T, no-max softmax, 128q/block (R11 config) ----------------
__global__ __launch_bounds__(256, 4) void attn_kernel(
    const u16* __restrict__ Q, const u16* __restrict__ Km, const u16* __restrict__ VT,
    u16* __restrict__ Opart, float* __restrict__ ML, int Nseq, int kvLen) {
  __shared__ u16 Ks[64 * 64];
  __shared__ u16 Vs[64 * 64];
  __shared__ u16 Ps[4 * 32 * 64];
  const int t = threadIdx.x;
  const int lane = t & 63;
  const int w = t >> 6;
  const int ln = lane & 15;
  const int quad = lane >> 4;
  const int h = blockIdx.y;
  const int q0 = blockIdx.x * 128;
  const int split = blockIdx.z;
  const int kvbase = split * kvLen;
  u16* Opw = Opart + (size_t)split * Nseq * 512;
  u16* Pw = &Ps[w * 32 * 64];

  short8 qf[2][2];
#pragma unroll
  for (int qt = 0; qt < 2; qt++)
#pragma unroll
    for (int ksi = 0; ksi < 2; ksi++)
      qf[qt][ksi] = *(const short8*)&Q[(size_t)(q0 + w * 32 + qt * 16 + ln) * 512 + h * 64 + ksi * 32 + quad * 8];

  floatx4 accO[2][4];
#pragma unroll
  for (int qt = 0; qt < 2; qt++)
#pragma unroll
    for (int td = 0; td < 4; td++) accO[qt][td] = floatx4{0.f, 0.f, 0.f, 0.f};
  float lsum[2] = {0.f, 0.f};

  for (int kv = 0; kv < kvLen; kv += 64) {
    const int kv0 = kvbase + kv;
    __syncthreads();
#pragma unroll
    for (int i = 0; i < 2; ++i) {
      int s = i * 256 + t;
      int row = s >> 3;
      int kb = (s & 7) ^ (row & 7);
      async16(Km + (size_t)(kv0 + row) * 512 + h * 64 + kb * 8, &Ks[(i * 256 + (t & ~63)) * 8]);
      async16(VT + (size_t)(h * 64 + row) * Nseq + kv0 + kb * 8, &Vs[(i * 256 + (t & ~63)) * 8]);
    }
    __syncthreads();

    floatx4 accS[2][4];
#pragma unroll
    for (int qt = 0; qt < 2; qt++)
#pragma unroll
      for (int tj = 0; tj < 4; tj++) accS[qt][tj] = floatx4{0.f, 0.f, 0.f, 0.f};
#pragma unroll
    for (int ksi = 0; ksi < 2; ksi++) {
      int kb = ksi * 4 + quad;
      short8 kf[4];
#pragma unroll
      for (int tj = 0; tj < 4; tj++) {
        int key = tj * 16 + ln;
        kf[tj] = *(const short8*)&Ks[(key * 8 + (kb ^ (key & 7))) * 8];
      }
#pragma unroll
      for (int qt = 0; qt < 2; qt++)
#pragma unroll
        for (int tj = 0; tj < 4; tj++)
          accS[qt][tj] = __builtin_amdgcn_mfma_f32_16x16x32_bf16(kf[tj], qf[qt][ksi], accS[qt][tj], 0, 0, 0);
    }

    // p = exp2(s); per-lane l; pack to LDS swizzled
#pragma unroll
    for (int qt = 0; qt < 2; qt++) {
      int q8 = (qt * 16 + ln) * 8;
#pragma unroll
      for (int tj = 0; tj < 4; tj++) {
        float p0 = fexp2(accS[qt][tj][0]);
        float p1 = fexp2(accS[qt][tj][1]);
        float p2 = fexp2(accS[qt][tj][2]);
        float p3 = fexp2(accS[qt][tj][3]);
        lsum[qt] += (p0 + p1) + (p2 + p3);
        __hip_bfloat162 a01 = __float22bfloat162_rn(float2{p0, p1});
        __hip_bfloat162 a23 = __float22bfloat162_rn(float2{p2, p3});
        uint2 pk;
        pk.x = *(unsigned*)&a01;
        pk.y = *(unsigned*)&a23;
        int kbx = tj * 2 + (quad >> 1);
        *(uint2*)&Pw[(q8 + (kbx ^ (ln & 7))) * 8 + (quad & 1) * 4] = pk;
      }
    }

    // O^T += V^T . P^T
#pragma unroll
    for (int ksi = 0; ksi < 2; ksi++) {
      int kb = ksi * 4 + quad;
      short8 pf[2];
#pragma unroll
      for (int qt = 0; qt < 2; qt++)
        pf[qt] = *(const short8*)&Pw[((qt * 16 + ln) * 8 + (kb ^ (ln & 7))) * 8];
#pragma unroll
      for (int td = 0; td < 4; td++) {
        int d = td * 16 + ln;
        short8 vf = *(const short8*)&Vs[(d * 8 + (kb ^ (d & 7))) * 8];
#pragma unroll
        for (int qt = 0; qt < 2; qt++)
          accO[qt][td] = __builtin_amdgcn_mfma_f32_16x16x32_bf16(vf, pf[qt], accO[qt][td], 0, 0, 0);
      }
    }
  }

#pragma unroll
  for (int qt = 0; qt < 2; qt++) {
    lsum[qt] += __shfl_xor(lsum[qt], 16);
    lsum[qt] += __shfl_xor(lsum[qt], 32);
  }
#pragma unroll
  for (int qt = 0; qt < 2; qt++) {
    int q = q0 + w * 32 + qt * 16 + ln;
#pragma unroll
    for (int td = 0; td < 4; td++) {
      __hip_bfloat162 p01 = __float22bfloat162_rn(float2{accO[qt][td][0], accO[qt][td][1]});
      __hip_bfloat162 p23 = __float22bfloat162_rn(float2{accO[qt][td][2], accO[qt][td][3]});
      uint2 pk;
      pk.x = *(unsigned*)&p01;
      pk.y = *(unsigned*)&p23;
      *(uint2*)&Opw[(size_t)q * 512 + h * 64 + td * 16 + quad * 4] = pk;
    }
    if (quad == 0)
      ML[((size_t)split * 8 + h) * Nseq + q] = lsum[qt];
  }
}

// ---------------- combine 4 splits + bf16 residual + LayerNorm (ln1) -> bf16 ----------------
__global__ __launch_bounds__(256) void ln_attn(
    const u16* __restrict__ Opart, const float* __restrict__ ML,
    const u16* __restrict__ t16, const float* __restrict__ g, const float* __restrict__ be,
    u16* __restrict__ o16) {
  int row = blockIdx.x;
  int t = threadIdx.x;
  size_t base = (size_t)row * 512;
  int c0 = 2 * t;
  int h = c0 >> 6;
  float lt = 0.f;
#pragma unroll
  for (int s = 0; s < 4; s++) lt += ML[((size_t)s * 8 + h) * 4096 + row];
  float a0 = 0.f, a1 = 0.f;
#pragma unroll
  for (int s = 0; s < 4; s++) {
    unsigned oo = *(const unsigned*)&Opart[(size_t)s * 4096 * 512 + base + c0];
    a0 += b2f((u16)(oo & 0xffff));
    a1 += b2f((u16)(oo >> 16));
  }
  unsigned tt = *(const unsigned*)&t16[base + c0];
  float inv = 1.0f / lt;
  float v0 = a0 * inv + b2f((u16)(tt & 0xffff));
  float v1 = a1 * inv + b2f((u16)(tt >> 16));
  float s = v0 + v1, ss = v0 * v0 + v1 * v1;
  for (int m = 1; m < 64; m <<= 1) { s += __shfl_xor(s, m); ss += __shfl_xor(ss, m); }
  __shared__ float sb[8];
  int w = t >> 6;
  if ((t & 63) == 0) { sb[w * 2] = s; sb[w * 2 + 1] = ss; }
  __syncthreads();
  s = sb[0] + sb[2] + sb[4] + sb[6];
  ss = sb[1] + sb[3] + sb[5] + sb[7];
  float mu = s / 512.f;
  float var = ss / 512.f - mu * mu;
  float rs = rsqrtf(var + 1e-5f);
  float2 gv = *(const float2*)&g[c0];
  float2 bv = *(const float2*)&be[c0];
  u16 r0 = f2b((v0 - mu) * rs * gv.x + bv.x);
  u16 r1 = f2b((v1 - mu) * rs * gv.y + bv.y);
  *(unsigned*)&o16[base + c0] = ((unsigned)r1 << 16) | r0;
}

// ---------------- LN2: (4 bf16 split-K partials + bf16 u) -> LayerNorm -> bf16 ----------------
__global__ __launch_bounds__(256) void ln_ff(
    const u16* __restrict__ zp, const u16* __restrict__ u,
    const float* __restrict__ g, const float* __restrict__ be, u16* __restrict__ o16) {
  int row = blockIdx.x;
  int t = threadIdx.x;
  size_t base = (size_t)row * 512;
  int c0 = 2 * t;
  unsigned uu = *(const unsigned*)&u[base + c0];
  float v0 = b2f((u16)(uu & 0xffff));
  float v1 = b2f((u16)(uu >> 16));
#pragma unroll
  for (int z = 0; z < 4; z++) {
    unsigned zz = *(const unsigned*)&zp[(size_t)z * 4096 * 512 + base + c0];
    v0 += b2f((u16)(zz & 0xffff));
    v1 += b2f((u16)(zz >> 16));
  }
  float s = v0 + v1, ss = v0 * v0 + v1 * v1;
  for (int m = 1; m < 64; m <<= 1) { s += __shfl_xor(s, m); ss += __shfl_xor(ss, m); }
  __shared__ float sb[8];
  int w = t >> 6;
  if ((t & 63) == 0) { sb[w * 2] = s; sb[w * 2 + 1] = ss; }
  __syncthreads();
  s = sb[0] + sb[2] + sb[4] + sb[6];
  ss = sb[1] + sb[3] + sb[5] + sb[7];
  float mu = s / 512.f;
  float var = ss / 512.f - mu * mu;
  float rs = rsqrtf(var + 1e-5f);
  float2 gv = *(const float2*)&g[c0];
  float2 bv = *(const float2*)&be[c0];
  u16 r0 = f2b((v0 - mu) * rs * gv.x + bv.x);
  u16 r1 = f2b((v1 - mu) * rs * gv.y + bv.y);
  *(unsigned*)&o16[base + c0] = ((unsigned)r1 << 16) | r0;
}

extern "C" void kernel_launch(void* const* d_in, const int* in_sizes, int n_in,
                              void* d_out, int out_size, void* d_ws, size_t ws_size,
                              hipStream_t stream) {
  const float* x = (const float*)d_in[0];
  const float* gn_g = (const float*)d_in[1];
  const float* gn_b = (const float*)d_in[2];
  const float* w_in = (const float*)d_in[3];
  const float* b_in = (const float*)d_in[4];
  const float* wq = (const float*)d_in[5];
  const float* wk = (const float*)d_in[6];
  const float* wv = (const float*)d_in[7];
  const float* ln1_g = (const float*)d_in[8];
  const float* ln1_b = (const float*)d_in[9];
  const float* ff_w1 = (const float*)d_in[10];
  const float* ff_b1 = (const float*)d_in[11];
  const float* ff_w2 = (const float*)d_in[12];
  const float* ff_b2 = (const float*)d_in[13];
  const float* ln2_g = (const float*)d_in[14];
  const float* ln2_b = (const float*)d_in[15];
  const float* w_out = (const float*)d_in[16];
  const float* b_out = (const float*)d_in[17];
  float* out = (float*)d_out;
  char* ws = (char*)d_ws;

  // ---- workspace layout (byte offsets; lifetime-audited) ----
  u16* w_in16 = (u16*)(ws + 0);                  // 0-0.25 MiB
  u16* wqkv16 = (u16*)(ws + 262144);             // 0.25-1.75 (wq|wk|wv)
  u16* fw116 = (u16*)(ws + 1835008);             // 1.75-3.75
  u16* fw216 = (u16*)(ws + 3932160);             // 3.75-5.75
  u16* wout16 = (u16*)(ws + 6029312);            // 5.75-6
  u16* u16b = (u16*)(ws + 6291456);              // 6-10   ln_attn -> ff1, ln_ff
  u16* zp = (u16*)(ws + 10485760);               // 10-26  ff2 partials -> ln_ff (over t16/qb/kb, dead)
  u16* t16 = (u16*)(ws + 14680064);              // 14-18  proj_in -> qkvt, ln_attn
  u16* qb = (u16*)(ws + 18874368);               // 18-22  qkvt -> attn
  u16* kb = (u16*)(ws + 23068672);               // 22-26  qkvt -> attn
  u16* vt = (u16*)(ws + 27262976);               // 26-30  qkvt -> attn
  u16* zb = (u16*)(ws + 27262976);               // 26-30  ln_ff -> proj_out (over vt, dead)
  u16* opart = (u16*)(ws + 31457280);            // 30-46  attn -> ln_attn (4 splits)
  u16* g16 = (u16*)(ws + 31457280);              // 30-46  ff1 -> ff2 (over opart, dead)
  float* ml = (float*)(ws + 48234496);           // 46-46.5 attn -> ln_attn
  u16* hn = (u16*)(ws + 49283072);               // 47-49  gn -> proj_in
  float2* cstats = (float2*)(ws + 51380224);     // 49+

  // weights convert (x4 vectorized, 3072 blocks) + per-channel GN stats (256 blocks)
  f2b_all<<<3328, 256, 0, stream>>>(w_in, wq, wk, wv, ff_w1, ff_w2, w_out, x,
                                    w_in16, wqkv16, fw116, fw216, wout16, cstats);
  gn_apply<<<256, 256, 0, stream>>>(x, cstats, gn_g, gn_b, hn);

  // t = hn @ w_in^T + b_in  -> bf16 (64x64 tiles, 512 blocks)
  gemm_s64<<<dim3(64, 8), 256, 0, stream>>>(hn, w_in16, b_in, nullptr, nullptr, t16,
                                            4096, 512, 256, FLAG_BIAS | FLAG_C16);
  // fused q|k (+CEXP on q) and V^T, one dispatch, 768 blocks
  gemm_qkvt<<<768, 256, 0, stream>>>(t16, wqkv16, qb, kb, vt);
  // attention: 128q/block, KV-split x4 (R11 config, LDS-staged)
  attn_kernel<<<dim3(32, 8, 4), 256, 0, stream>>>(qb, kb, vt, opart, ml, 4096, 1024);
  // combine + LN1 (residual from t16) -> bf16
  ln_attn<<<4096, 256, 0, stream>>>(opart, ml, t16, ln1_g, ln1_b, u16b);
  // ff1: gelu(u @ w1^T + b1) -> bf16
  gemm_big<<<dim3(32, 16), 256, 0, stream>>>(u16b, fw116, ff_b1, g16,
                                             4096, 2048, 512, FLAG_BIAS | FLAG_GELU | FLAG_C16);
  // ff2: split-K x4 -> four bf16 partials
  gemm_big<<<dim3(32, 4, 4), 256, 0, stream>>>(g16, fw216, ff_b2, zp,
                                               4096, 512, 2048, FLAG_BIAS | FLAG_CZ);
  // z = LN(sum zp + u) -> bf16
  ln_ff<<<4096, 256, 0, stream>>>(zp, u16b, ln2_g, ln2_b, zb);
  // out = W_out @ z^T (+b_out per-row, +x), 64x64 tiles, 256 blocks
  gemm_s64<<<dim3(4, 64), 256, 0, stream>>>(wout16, zb, b_out, x, out, nullptr,
                                            256, 4096, 512, FLAG_FINAL);
}

// Round 14
// 221.458 us; speedup vs baseline: 1.3584x; 1.0288x over previous
//
#include <hip/hip_runtime.h>
#include <hip/hip_bf16.h>

typedef unsigned short u16;
typedef __attribute__((ext_vector_type(8))) short short8;
typedef __attribute__((ext_vector_type(4))) float floatx4;

#define LOG2E 1.44269504088896f
#define CEXP (0.125f * LOG2E)   // folded into Q at the QK epilogue

static __device__ __forceinline__ u16 f2b(float f) {
  union { float f; unsigned u; } v; v.f = f;
  unsigned r = v.u + 0x7fffu + ((v.u >> 16) & 1u);
  return (u16)(r >> 16);
}
static __device__ __forceinline__ float b2f(u16 b) {
  union { float f; unsigned u; } v; v.u = ((unsigned)b) << 16;
  return v.f;
}
static __device__ __forceinline__ void async16(const u16* g, u16* l) {
  __builtin_amdgcn_global_load_lds(
      (const __attribute__((address_space(1))) unsigned int*)g,
      (__attribute__((address_space(3))) unsigned int*)l, 16, 0, 0);
}
static __device__ __forceinline__ float fexp2(float x) {
  return __builtin_amdgcn_exp2f(x);
}

// ---------------- weights fp32 -> bf16 (x4 vectorized) + per-channel GN stats ----------------
__global__ __launch_bounds__(256) void f2b_all(
    const float* __restrict__ s0, const float* __restrict__ s1, const float* __restrict__ s2,
    const float* __restrict__ s3, const float* __restrict__ s4, const float* __restrict__ s5,
    const float* __restrict__ s6, const float* __restrict__ x,
    u16* __restrict__ d_win, u16* __restrict__ d_qkv, u16* __restrict__ d_f1,
    u16* __restrict__ d_f2, u16* __restrict__ d_wout, float2* __restrict__ cstats) {
  if (blockIdx.x >= 3072) {   // per-channel stats: one block per channel
    int c = blockIdx.x - 3072;
    const float4* p4 = (const float4*)(x + (size_t)c * 4096);
    float s = 0.f, ss = 0.f;
#pragma unroll
    for (int j = 0; j < 4; j++) {
      float4 v = p4[j * 256 + threadIdx.x];
      s += v.x + v.y + v.z + v.w;
      ss += v.x * v.x + v.y * v.y + v.z * v.z + v.w * v.w;
    }
    for (int m = 1; m < 64; m <<= 1) { s += __shfl_xor(s, m); ss += __shfl_xor(ss, m); }
    __shared__ float sb[8];
    int w = threadIdx.x >> 6;
    if ((threadIdx.x & 63) == 0) { sb[w * 2] = s; sb[w * 2 + 1] = ss; }
    __syncthreads();
    if (threadIdx.x == 0)
      cstats[c] = float2{sb[0] + sb[2] + sb[4] + sb[6], sb[1] + sb[3] + sb[5] + sb[7]};
    return;
  }
  int i = blockIdx.x * 256 + threadIdx.x;   // x4 elements per thread
  const float* src;
  u16* dst;
  if (i < 32768) { src = s0; dst = d_win; }
  else if ((i -= 32768) < 65536) { src = s1; dst = d_qkv; }
  else if ((i -= 65536) < 65536) { src = s2; dst = d_qkv + 262144; }
  else if ((i -= 65536) < 65536) { src = s3; dst = d_qkv + 524288; }
  else if ((i -= 65536) < 262144) { src = s4; dst = d_f1; }
  else if ((i -= 262144) < 262144) { src = s5; dst = d_f2; }
  else { i -= 262144; src = s6; dst = d_wout; }   // i in [0, 32768)
  float4 v = *(const float4*)&src[i * 4];
  ushort4 o;
  o.x = f2b(v.x); o.y = f2b(v.y); o.z = f2b(v.z); o.w = f2b(v.w);
  *(ushort4*)&dst[i * 4] = o;
}

// ---------------- GroupNorm apply + LDS transpose to (N,C) bf16, 512 blocks ----------------
__global__ __launch_bounds__(256) void gn_apply(const float* __restrict__ x, const float2* __restrict__ cstats,
                                                const float* __restrict__ gg, const float* __restrict__ gb,
                                                u16* __restrict__ hn) {
  __shared__ float tile[256 * 9];
  __shared__ float gmu[32], grs[32];
  int t = threadIdx.x;
  if (t < 32) {
    float s = 0.f, ss = 0.f;
#pragma unroll
    for (int j = 0; j < 8; j++) { float2 p = cstats[t * 8 + j]; s += p.x; ss += p.y; }
    float mu = s / 32768.f;
    gmu[t] = mu;
    grs[t] = rsqrtf(ss / 32768.f - mu * mu + 1e-5f);
  }
  __syncthreads();
  int n0 = blockIdx.x * 8;
#pragma unroll
  for (int j = 0; j < 2; j++) {
    int c = j * 128 + (t >> 1);
    int nl = (t & 1) * 4;
    float4 v = *(const float4*)&x[(size_t)c * 4096 + n0 + nl];
    float ga = gg[c] * grs[c >> 3];
    float bb = gb[c] - gmu[c >> 3] * ga;
    tile[c * 9 + nl + 0] = v.x * ga + bb;
    tile[c * 9 + nl + 1] = v.y * ga + bb;
    tile[c * 9 + nl + 2] = v.z * ga + bb;
    tile[c * 9 + nl + 3] = v.w * ga + bb;
  }
  __syncthreads();
#pragma unroll
  for (int j = 0; j < 8; j++)
    hn[(size_t)(n0 + j) * 256 + t] = f2b(tile[t * 9 + j]);
}

#define FLAG_BIAS 1
#define FLAG_GELU 2
#define FLAG_C16 8
#define FLAG_FINAL 32   // C32[m*N+n] = v + bias[m] + resid[m*N+n]
#define FLAG_CZ 64      // C16[z*M*N + m*N + n] = bf16(v), bias on z==0 only

// ---------------- GEMM 128x64 tile (proj_in) ----------------
__global__ __launch_bounds__(256) void gemm_bt(
    const u16* __restrict__ A, const u16* __restrict__ B, const float* __restrict__ bias,
    u16* __restrict__ C16, int M, int N, int K, int flags) {
  __shared__ u16 As[128 * 64];
  __shared__ u16 Bs[64 * 64];
  const int t = threadIdx.x;
  const int lane = t & 63;
  const int w = t >> 6;
  const int ln = lane & 15;
  const int quad = lane >> 4;
  const int m0 = blockIdx.x * 128;
  const int n0 = blockIdx.y * 64;
  const int wm = (w >> 1) * 64;
  const int wn = (w & 1) * 32;

  floatx4 acc[4][2];
#pragma unroll
  for (int i = 0; i < 4; i++)
#pragma unroll
    for (int j = 0; j < 2; j++) acc[i][j] = floatx4{0.f, 0.f, 0.f, 0.f};

  for (int k0 = 0; k0 < K; k0 += 64) {
    __syncthreads();
#pragma unroll
    for (int i = 0; i < 4; ++i) {
      int s = i * 256 + t;
      int row = s >> 3;
      int kb = (s & 7) ^ (row & 7);
      async16(A + (size_t)(m0 + row) * K + k0 + kb * 8, &As[(i * 256 + (t & ~63)) * 8]);
    }
#pragma unroll
    for (int i = 0; i < 2; ++i) {
      int s = i * 256 + t;
      int row = s >> 3;
      int kb = (s & 7) ^ (row & 7);
      async16(B + (size_t)(n0 + row) * K + k0 + kb * 8, &Bs[(i * 256 + (t & ~63)) * 8]);
    }
    __syncthreads();
#pragma unroll
    for (int ksi = 0; ksi < 2; ksi++) {
      short8 af[4], bfr[2];
      int kb = ksi * 4 + quad;
#pragma unroll
      for (int i = 0; i < 4; i++) {
        int m = wm + i * 16 + ln;
        af[i] = *(const short8*)&As[(m * 8 + (kb ^ (m & 7))) * 8];
      }
#pragma unroll
      for (int j = 0; j < 2; j++) {
        int n = wn + j * 16 + ln;
        bfr[j] = *(const short8*)&Bs[(n * 8 + (kb ^ (n & 7))) * 8];
      }
#pragma unroll
      for (int i = 0; i < 4; i++)
#pragma unroll
        for (int j = 0; j < 2; j++)
          acc[i][j] = __builtin_amdgcn_mfma_f32_16x16x32_bf16(af[i], bfr[j], acc[i][j], 0, 0, 0);
    }
  }

#pragma unroll
  for (int i = 0; i < 4; i++) {
#pragma unroll
    for (int j = 0; j < 2; j++) {
      int n = n0 + wn + j * 16 + ln;
      float bv = (flags & FLAG_BIAS) ? bias[n] : 0.f;
#pragma unroll
      for (int r = 0; r < 4; r++) {
        int m = m0 + wm + i * 16 + quad * 4 + r;
        float v = acc[i][j][r] + bv;
        if (flags & FLAG_C16) C16[(size_t)m * N + n] = f2b(v);
      }
    }
  }
}

// ---------------- GEMM 64x64 tile (proj_out: row-bias + resid fp32) ----------------
__global__ __launch_bounds__(256) void gemm_s64(
    const u16* __restrict__ A, const u16* __restrict__ B, const float* __restrict__ brow,
    const float* __restrict__ resid, float* __restrict__ C32, int N, int K) {
  __shared__ u16 As[64 * 64];
  __shared__ u16 Bs[64 * 64];
  const int t = threadIdx.x;
  const int lane = t & 63;
  const int w = t >> 6;
  const int ln = lane & 15;
  const int quad = lane >> 4;
  const int m0 = blockIdx.x * 64;
  const int n0 = blockIdx.y * 64;
  const int wm = (w >> 1) * 32;
  const int wn = (w & 1) * 32;

  floatx4 acc[2][2];
#pragma unroll
  for (int i = 0; i < 2; i++)
#pragma unroll
    for (int j = 0; j < 2; j++) acc[i][j] = floatx4{0.f, 0.f, 0.f, 0.f};

  for (int k0 = 0; k0 < K; k0 += 64) {
    __syncthreads();
#pragma unroll
    for (int i = 0; i < 2; ++i) {
      int s = i * 256 + t;
      int row = s >> 3;
      int kb = (s & 7) ^ (row & 7);
      async16(A + (size_t)(m0 + row) * K + k0 + kb * 8, &As[(i * 256 + (t & ~63)) * 8]);
    }
#pragma unroll
    for (int i = 0; i < 2; ++i) {
      int s = i * 256 + t;
      int row = s >> 3;
      int kb = (s & 7) ^ (row & 7);
      async16(B + (size_t)(n0 + row) * K + k0 + kb * 8, &Bs[(i * 256 + (t & ~63)) * 8]);
    }
    __syncthreads();
#pragma unroll
    for (int ksi = 0; ksi < 2; ksi++) {
      short8 af[2], bfr[2];
      int kb = ksi * 4 + quad;
#pragma unroll
      for (int i = 0; i < 2; i++) {
        int m = wm + i * 16 + ln;
        af[i] = *(const short8*)&As[(m * 8 + (kb ^ (m & 7))) * 8];
        int n = wn + i * 16 + ln;
        bfr[i] = *(const short8*)&Bs[(n * 8 + (kb ^ (n & 7))) * 8];
      }
#pragma unroll
      for (int i = 0; i < 2; i++)
#pragma unroll
        for (int j = 0; j < 2; j++)
          acc[i][j] = __builtin_amdgcn_mfma_f32_16x16x32_bf16(af[i], bfr[j], acc[i][j], 0, 0, 0);
    }
  }

#pragma unroll
  for (int i = 0; i < 2; i++) {
#pragma unroll
    for (int j = 0; j < 2; j++) {
      int n = n0 + wn + j * 16 + ln;
#pragma unroll
      for (int r = 0; r < 4; r++) {
        int m = m0 + wm + i * 16 + quad * 4 + r;
        C32[(size_t)m * N + n] = acc[i][j][r] + brow[m] + resid[(size_t)m * N + n];
      }
    }
  }
}

// ---------------- GEMM 128x128 tile (ff1, ff2 split-K bf16 partials) ----------------
__global__ __launch_bounds__(256) void gemm_big(
    const u16* __restrict__ A, const u16* __restrict__ B, const float* __restrict__ bias,
    u16* __restrict__ C16, int M, int N, int K, int flags) {
  __shared__ u16 As[128 * 64];
  __shared__ u16 Bs[128 * 64];
  const int t = threadIdx.x;
  const int lane = t & 63;
  const int w = t >> 6;
  const int ln = lane & 15;
  const int quad = lane >> 4;
  const int m0 = blockIdx.x * 128;
  const int n0 = blockIdx.y * 128;
  const int wm = (w >> 1) * 64;
  const int wn = (w & 1) * 64;
  const int kper = K / gridDim.z;
  const int kbeg = blockIdx.z * kper;

  floatx4 acc[4][4];
#pragma unroll
  for (int i = 0; i < 4; i++)
#pragma unroll
    for (int j = 0; j < 4; j++) acc[i][j] = floatx4{0.f, 0.f, 0.f, 0.f};

  for (int k0 = kbeg; k0 < kbeg + kper; k0 += 64) {
    __syncthreads();
#pragma unroll
    for (int i = 0; i < 4; ++i) {
      int s = i * 256 + t;
      int row = s >> 3;
      int kb = (s & 7) ^ (row & 7);
      async16(A + (size_t)(m0 + row) * K + k0 + kb * 8, &As[(i * 256 + (t & ~63)) * 8]);
      async16(B + (size_t)(n0 + row) * K + k0 + kb * 8, &Bs[(i * 256 + (t & ~63)) * 8]);
    }
    __syncthreads();
#pragma unroll
    for (int ksi = 0; ksi < 2; ksi++) {
      short8 af[4], bfr[4];
      int kb = ksi * 4 + quad;
#pragma unroll
      for (int i = 0; i < 4; i++) {
        int m = wm + i * 16 + ln;
        af[i] = *(const short8*)&As[(m * 8 + (kb ^ (m & 7))) * 8];
        int n = wn + i * 16 + ln;
        bfr[i] = *(const short8*)&Bs[(n * 8 + (kb ^ (n & 7))) * 8];
      }
#pragma unroll
      for (int i = 0; i < 4; i++)
#pragma unroll
        for (int j = 0; j < 4; j++)
          acc[i][j] = __builtin_amdgcn_mfma_f32_16x16x32_bf16(af[i], bfr[j], acc[i][j], 0, 0, 0);
    }
  }

  u16* Cdst = (flags & FLAG_CZ) ? C16 + (size_t)blockIdx.z * M * N : C16;
#pragma unroll
  for (int i = 0; i < 4; i++) {
#pragma unroll
    for (int j = 0; j < 4; j++) {
      int n = n0 + wn + j * 16 + ln;
      float bv = ((flags & FLAG_BIAS) && blockIdx.z == 0) ? bias[n] : 0.f;
#pragma unroll
      for (int r = 0; r < 4; r++) {
        int m = m0 + wm + i * 16 + quad * 4 + r;
        float v = acc[i][j][r] + bv;
        if (flags & FLAG_GELU) v = 0.5f * v * (1.f + erff(v * 0.70710678118f));
        Cdst[(size_t)m * N + n] = f2b(v);
      }
    }
  }
}

// ---------------- merged q|k + V^T GEMM, 64x128 tiles, one dispatch ----------------
__global__ __launch_bounds__(256) void gemm_qkvt(
    const u16* __restrict__ T, const u16* __restrict__ Wqkv,
    u16* __restrict__ Cq, u16* __restrict__ Ck, u16* __restrict__ CvT) {
  __shared__ u16 As[64 * 64];
  __shared__ u16 Bs[128 * 64];
  const int t = threadIdx.x;
  const int lane = t & 63;
  const int w = t >> 6;
  const int ln = lane & 15;
  const int quad = lane >> 4;
  const int bx = blockIdx.x;
  const bool isv = bx >= 512;
  const u16* A;
  const u16* B;
  int m0, n0;
  if (!isv) {
    m0 = (bx >> 3) * 64;
    n0 = (bx & 7) * 128;
    A = T;
    B = Wqkv;
  } else {
    int b2 = bx - 512;
    m0 = (b2 >> 5) * 64;
    n0 = (b2 & 31) * 128;
    A = Wqkv + 2 * 512 * 512;   // wv
    B = T;
  }
  const int wm = (w >> 1) * 32;
  const int wn = (w & 1) * 64;

  floatx4 acc[2][4];
#pragma unroll
  for (int i = 0; i < 2; i++)
#pragma unroll
    for (int j = 0; j < 4; j++) acc[i][j] = floatx4{0.f, 0.f, 0.f, 0.f};

  for (int k0 = 0; k0 < 512; k0 += 64) {
    __syncthreads();
#pragma unroll
    for (int i = 0; i < 2; ++i) {
      int s = i * 256 + t;
      int row = s >> 3;
      int kb = (s & 7) ^ (row & 7);
      async16(A + (size_t)(m0 + row) * 512 + k0 + kb * 8, &As[(i * 256 + (t & ~63)) * 8]);
    }
#pragma unroll
    for (int i = 0; i < 4; ++i) {
      int s = i * 256 + t;
      int row = s >> 3;
      int kb = (s & 7) ^ (row & 7);
      async16(B + (size_t)(n0 + row) * 512 + k0 + kb * 8, &Bs[(i * 256 + (t & ~63)) * 8]);
    }
    __syncthreads();
#pragma unroll
    for (int ksi = 0; ksi < 2; ksi++) {
      short8 af[2], bfr[4];
      int kb = ksi * 4 + quad;
#pragma unroll
      for (int i = 0; i < 2; i++) {
        int m = wm + i * 16 + ln;
        af[i] = *(const short8*)&As[(m * 8 + (kb ^ (m & 7))) * 8];
      }
#pragma unroll
      for (int j = 0; j < 4; j++) {
        int n = wn + j * 16 + ln;
        bfr[j] = *(const short8*)&Bs[(n * 8 + (kb ^ (n & 7))) * 8];
      }
#pragma unroll
      for (int i = 0; i < 2; i++)
#pragma unroll
        for (int j = 0; j < 4; j++)
          acc[i][j] = __builtin_amdgcn_mfma_f32_16x16x32_bf16(af[i], bfr[j], acc[i][j], 0, 0, 0);
    }
  }

#pragma unroll
  for (int i = 0; i < 2; i++) {
#pragma unroll
    for (int j = 0; j < 4; j++) {
      int n = n0 + wn + j * 16 + ln;
#pragma unroll
      for (int r = 0; r < 4; r++) {
        int m = m0 + wm + i * 16 + quad * 4 + r;
        float v = acc[i][j][r];
        if (isv) CvT[(size_t)m * 4096 + n] = f2b(v);
        else if (n < 512) Cq[(size_t)m * 512 + n] = f2b(v * CEXP);   // Q pre-scaled
        else Ck[(size_t)m * 512 + (n - 512)] = f2b(v);
      }
    }
  }
}

// ---------------- flash attention: 512 threads, 8 waves share one K/V tile ----------------
// Per-wave work identical to R11 (32 q/wave); staging traffic and barriers halve per q.
__global__ __launch_bounds__(512) void attn_kernel(
    const u16* __restrict__ Q, const u16* __restrict__ Km, const u16* __restrict__ VT,
    u16* __restrict__ Opart, float* __restrict__ ML, int Nseq, int kvLen) {
  __shared__ u16 Ks[64 * 64];
  __shared__ u16 Vs[64 * 64];
  __shared__ u16 Ps[8 * 32 * 64];
  const int t = threadIdx.x;
  const int lane = t & 63;
  const int w = t >> 6;            // 0..7
  const int ln = lane & 15;
  const int quad = lane >> 4;
  const int h = blockIdx.y;
  const int q0 = blockIdx.x * 256;
  const int split = blockIdx.z;
  const int kvbase = split * kvLen;
  u16* Opw = Opart + (size_t)split * Nseq * 512;
  u16* Pw = &Ps[w * 32 * 64];

  short8 qf[2][2];
#pragma unroll
  for (int qt = 0; qt < 2; qt++)
#pragma unroll
    for (int ksi = 0; ksi < 2; ksi++)
      qf[qt][ksi] = *(const short8*)&Q[(size_t)(q0 + w * 32 + qt * 16 + ln) * 512 + h * 64 + ksi * 32 + quad * 8];

  floatx4 accO[2][4];
#pragma unroll
  for (int qt = 0; qt < 2; qt++)
#pragma unroll
    for (int td = 0; td < 4; td++) accO[qt][td] = floatx4{0.f, 0.f, 0.f, 0.f};
  float lsum[2] = {0.f, 0.f};

  // staging: 512 chunks of 16B per buffer, one per thread
  const int srow = t >> 3;
  const int skb = (t & 7) ^ (srow & 7);

  for (int kv = 0; kv < kvLen; kv += 64) {
    const int kv0 = kvbase + kv;
    __syncthreads();
    async16(Km + (size_t)(kv0 + srow) * 512 + h * 64 + skb * 8, &Ks[(t & ~63) * 8]);
    async16(VT + (size_t)(h * 64 + srow) * Nseq + kv0 + skb * 8, &Vs[(t & ~63) * 8]);
    __syncthreads();

    floatx4 accS[2][4];
#pragma unroll
    for (int qt = 0; qt < 2; qt++)
#pragma unroll
      for (int tj = 0; tj < 4; tj++) accS[qt][tj] = floatx4{0.f, 0.f, 0.f, 0.f};
#pragma unroll
    for (int ksi = 0; ksi < 2; ksi++) {
      int kb = ksi * 4 + quad;
      short8 kf[4];
#pragma unroll
      for (int tj = 0; tj < 4; tj++) {
        int key = tj * 16 + ln;
        kf[tj] = *(const short8*)&Ks[(key * 8 + (kb ^ (key & 7))) * 8];
      }
#pragma unroll
      for (int qt = 0; qt < 2; qt++)
#pragma unroll
        for (int tj = 0; tj < 4; tj++)
          accS[qt][tj] = __builtin_amdgcn_mfma_f32_16x16x32_bf16(kf[tj], qf[qt][ksi], accS[qt][tj], 0, 0, 0);
    }

    // p = exp2(s); per-lane l; pack to wave-private LDS (swizzled)
#pragma unroll
    for (int qt = 0; qt < 2; qt++) {
      int q8 = (qt * 16 + ln) * 8;
#pragma unroll
      for (int tj = 0; tj < 4; tj++) {
        float p0 = fexp2(accS[qt][tj][0]);
        float p1 = fexp2(accS[qt][tj][1]);
        float p2 = fexp2(accS[qt][tj][2]);
        float p3 = fexp2(accS[qt][tj][3]);
        lsum[qt] += (p0 + p1) + (p2 + p3);
        __hip_bfloat162 a01 = __float22bfloat162_rn(float2{p0, p1});
        __hip_bfloat162 a23 = __float22bfloat162_rn(float2{p2, p3});
        uint2 pk;
        pk.x = *(unsigned*)&a01;
        pk.y = *(unsigned*)&a23;
        int kbx = tj * 2 + (quad >> 1);
        *(uint2*)&Pw[(q8 + (kbx ^ (ln & 7))) * 8 + (quad & 1) * 4] = pk;
      }
    }

    // O^T += V^T . P^T
#pragma unroll
    for (int ksi = 0; ksi < 2; ksi++) {
      int kb = ksi * 4 + quad;
      short8 pf[2];
#pragma unroll
      for (int qt = 0; qt < 2; qt++)
        pf[qt] = *(const short8*)&Pw[((qt * 16 + ln) * 8 + (kb ^ (ln & 7))) * 8];
#pragma unroll
      for (int td = 0; td < 4; td++) {
        int d = td * 16 + ln;
        short8 vf = *(const short8*)&Vs[(d * 8 + (kb ^ (d & 7))) * 8];
#pragma unroll
        for (int qt = 0; qt < 2; qt++)
          accO[qt][td] = __builtin_amdgcn_mfma_f32_16x16x32_bf16(vf, pf[qt], accO[qt][td], 0, 0, 0);
      }
    }
  }

#pragma unroll
  for (int qt = 0; qt < 2; qt++) {
    lsum[qt] += __shfl_xor(lsum[qt], 16);
    lsum[qt] += __shfl_xor(lsum[qt], 32);
  }
#pragma unroll
  for (int qt = 0; qt < 2; qt++) {
    int q = q0 + w * 32 + qt * 16 + ln;
#pragma unroll
    for (int td = 0; td < 4; td++) {
      __hip_bfloat162 p01 = __float22bfloat162_rn(float2{accO[qt][td][0], accO[qt][td][1]});
      __hip_bfloat162 p23 = __float22bfloat162_rn(float2{accO[qt][td][2], accO[qt][td][3]});
      uint2 pk;
      pk.x = *(unsigned*)&p01;
      pk.y = *(unsigned*)&p23;
      *(uint2*)&Opw[(size_t)q * 512 + h * 64 + td * 16 + quad * 4] = pk;
    }
    if (quad == 0)
      ML[((size_t)split * 8 + h) * Nseq + q] = lsum[qt];
  }
}

// ---------------- combine 4 splits + bf16 residual + LayerNorm (ln1) -> bf16 ----------------
__global__ __launch_bounds__(256) void ln_attn(
    const u16* __restrict__ Opart, const float* __restrict__ ML,
    const u16* __restrict__ t16, const float* __restrict__ g, const float* __restrict__ be,
    u16* __restrict__ o16) {
  int row = blockIdx.x;
  int t = threadIdx.x;
  size_t base = (size_t)row * 512;
  int c0 = 2 * t;
  int h = c0 >> 6;
  float lt = 0.f;
#pragma unroll
  for (int s = 0; s < 4; s++) lt += ML[((size_t)s * 8 + h) * 4096 + row];
  float a0 = 0.f, a1 = 0.f;
#pragma unroll
  for (int s = 0; s < 4; s++) {
    unsigned oo = *(const unsigned*)&Opart[(size_t)s * 4096 * 512 + base + c0];
    a0 += b2f((u16)(oo & 0xffff));
    a1 += b2f((u16)(oo >> 16));
  }
  unsigned tt = *(const unsigned*)&t16[base + c0];
  float inv = 1.0f / lt;
  float v0 = a0 * inv + b2f((u16)(tt & 0xffff));
  float v1 = a1 * inv + b2f((u16)(tt >> 16));
  float s = v0 + v1, ss = v0 * v0 + v1 * v1;
  for (int m = 1; m < 64; m <<= 1) { s += __shfl_xor(s, m); ss += __shfl_xor(ss, m); }
  __shared__ float sb[8];
  int w = t >> 6;
  if ((t & 63) == 0) { sb[w * 2] = s; sb[w * 2 + 1] = ss; }
  __syncthreads();
  s = sb[0] + sb[2] + sb[4] + sb[6];
  ss = sb[1] + sb[3] + sb[5] + sb[7];
  float mu = s / 512.f;
  float var = ss / 512.f - mu * mu;
  float rs = rsqrtf(var + 1e-5f);
  float2 gv = *(const float2*)&g[c0];
  float2 bv = *(const float2*)&be[c0];
  u16 r0 = f2b((v0 - mu) * rs * gv.x + bv.x);
  u16 r1 = f2b((v1 - mu) * rs * gv.y + bv.y);
  *(unsigned*)&o16[base + c0] = ((unsigned)r1 << 16) | r0;
}

// ---------------- LN2: (4 bf16 split-K partials + bf16 u) -> LayerNorm -> bf16 ----------------
__global__ __launch_bounds__(256) void ln_ff(
    const u16* __restrict__ zp, const u16* __restrict__ u,
    const float* __restrict__ g, const float* __restrict__ be, u16* __restrict__ o16) {
  int row = blockIdx.x;
  int t = threadIdx.x;
  size_t base = (size_t)row * 512;
  int c0 = 2 * t;
  unsigned uu = *(const unsigned*)&u[base + c0];
  float v0 = b2f((u16)(uu & 0xffff));
  float v1 = b2f((u16)(uu >> 16));
#pragma unroll
  for (int z = 0; z < 4; z++) {
    unsigned zz = *(const unsigned*)&zp[(size_t)z * 4096 * 512 + base + c0];
    v0 += b2f((u16)(zz & 0xffff));
    v1 += b2f((u16)(zz >> 16));
  }
  float s = v0 + v1, ss = v0 * v0 + v1 * v1;
  for (int m = 1; m < 64; m <<= 1) { s += __shfl_xor(s, m); ss += __shfl_xor(ss, m); }
  __shared__ float sb[8];
  int w = t >> 6;
  if ((t & 63) == 0) { sb[w * 2] = s; sb[w * 2 + 1] = ss; }
  __syncthreads();
  s = sb[0] + sb[2] + sb[4] + sb[6];
  ss = sb[1] + sb[3] + sb[5] + sb[7];
  float mu = s / 512.f;
  float var = ss / 512.f - mu * mu;
  float rs = rsqrtf(var + 1e-5f);
  float2 gv = *(const float2*)&g[c0];
  float2 bv = *(const float2*)&be[c0];
  u16 r0 = f2b((v0 - mu) * rs * gv.x + bv.x);
  u16 r1 = f2b((v1 - mu) * rs * gv.y + bv.y);
  *(unsigned*)&o16[base + c0] = ((unsigned)r1 << 16) | r0;
}

extern "C" void kernel_launch(void* const* d_in, const int* in_sizes, int n_in,
                              void* d_out, int out_size, void* d_ws, size_t ws_size,
                              hipStream_t stream) {
  const float* x = (const float*)d_in[0];
  const float* gn_g = (const float*)d_in[1];
  const float* gn_b = (const float*)d_in[2];
  const float* w_in = (const float*)d_in[3];
  const float* b_in = (const float*)d_in[4];
  const float* wq = (const float*)d_in[5];
  const float* wk = (const float*)d_in[6];
  const float* wv = (const float*)d_in[7];
  const float* ln1_g = (const float*)d_in[8];
  const float* ln1_b = (const float*)d_in[9];
  const float* ff_w1 = (const float*)d_in[10];
  const float* ff_b1 = (const float*)d_in[11];
  const float* ff_w2 = (const float*)d_in[12];
  const float* ff_b2 = (const float*)d_in[13];
  const float* ln2_g = (const float*)d_in[14];
  const float* ln2_b = (const float*)d_in[15];
  const float* w_out = (const float*)d_in[16];
  const float* b_out = (const float*)d_in[17];
  float* out = (float*)d_out;
  char* ws = (char*)d_ws;

  // ---- workspace layout (byte offsets; lifetime-audited) ----
  u16* w_in16 = (u16*)(ws + 0);                  // 0-0.25 MiB
  u16* wqkv16 = (u16*)(ws + 262144);             // 0.25-1.75 (wq|wk|wv)
  u16* fw116 = (u16*)(ws + 1835008);             // 1.75-3.75
  u16* fw216 = (u16*)(ws + 3932160);             // 3.75-5.75
  u16* wout16 = (u16*)(ws + 6029312);            // 5.75-6
  u16* u16b = (u16*)(ws + 6291456);              // 6-10   ln_attn -> ff1, ln_ff
  u16* zp = (u16*)(ws + 10485760);               // 10-26  ff2 partials -> ln_ff (over t16/qb/kb, dead)
  u16* t16 = (u16*)(ws + 14680064);              // 14-18  proj_in -> qkvt, ln_attn
  u16* qb = (u16*)(ws + 18874368);               // 18-22  qkvt -> attn
  u16* kb = (u16*)(ws + 23068672);               // 22-26  qkvt -> attn
  u16* vt = (u16*)(ws + 27262976);               // 26-30  qkvt -> attn
  u16* zb = (u16*)(ws + 27262976);               // 26-30  ln_ff -> proj_out (over vt, dead)
  u16* opart = (u16*)(ws + 31457280);            // 30-46  attn -> ln_attn (4 splits)
  u16* g16 = (u16*)(ws + 31457280);              // 30-46  ff1 -> ff2 (over opart, dead)
  float* ml = (float*)(ws + 48234496);           // 46-46.5 attn -> ln_attn
  u16* hn = (u16*)(ws + 49283072);               // 47-49  gn -> proj_in
  float2* cstats = (float2*)(ws + 51380224);     // 49+

  // weights convert (x4 vectorized, 3072 blocks) + per-channel GN stats (256 blocks)
  f2b_all<<<3328, 256, 0, stream>>>(w_in, wq, wk, wv, ff_w1, ff_w2, w_out, x,
                                    w_in16, wqkv16, fw116, fw216, wout16, cstats);
  gn_apply<<<512, 256, 0, stream>>>(x, cstats, gn_g, gn_b, hn);

  // t = hn @ w_in^T + b_in  -> bf16 (128x64 tiles, R11 config)
  gemm_bt<<<dim3(32, 8), 256, 0, stream>>>(hn, w_in16, b_in, t16,
                                           4096, 512, 256, FLAG_BIAS | FLAG_C16);
  // fused q|k (+CEXP on q) and V^T, one dispatch, 768 blocks
  gemm_qkvt<<<768, 256, 0, stream>>>(t16, wqkv16, qb, kb, vt);
  // attention: 512 threads, 256q/block, KV-split x4 -> 512 blocks (2/CU)
  attn_kernel<<<dim3(16, 8, 4), 512, 0, stream>>>(qb, kb, vt, opart, ml, 4096, 1024);
  // combine + LN1 (residual from t16) -> bf16
  ln_attn<<<4096, 256, 0, stream>>>(opart, ml, t16, ln1_g, ln1_b, u16b);
  // ff1: gelu(u @ w1^T + b1) -> bf16
  gemm_big<<<dim3(32, 16), 256, 0, stream>>>(u16b, fw116, ff_b1, g16,
                                             4096, 2048, 512, FLAG_BIAS | FLAG_GELU | FLAG_C16);
  // ff2: split-K x4 -> four bf16 partials
  gemm_big<<<dim3(32, 4, 4), 256, 0, stream>>>(g16, fw216, ff_b2, zp,
                                               4096, 512, 2048, FLAG_BIAS | FLAG_CZ);
  // z = LN(sum zp + u) -> bf16
  ln_ff<<<4096, 256, 0, stream>>>(zp, u16b, ln2_g, ln2_b, zb);
  // out = W_out @ z^T (+b_out per-row, +x), 64x64 tiles, 256 blocks
  gemm_s64<<<dim3(4, 64), 256, 0, stream>>>(wout16, zb, b_out, x, out, 4096, 512);
}